// Round 5
// baseline (323.594 us; speedup 1.0000x reference)
//
#include <hip/hip_runtime.h>
#include <math.h>

constexpr int BB = 64, NN = 512, DD = 128, UU = 64;
constexpr float KCOUL = 14.399645351950548f;
constexpr float NOISEF = 1e-8f;
#define M_PIF 3.14159265358979323846f

typedef __attribute__((ext_vector_type(8))) short bfrag;   // 8 bf16 (4 VGPRs)
typedef __attribute__((ext_vector_type(4))) float ffrag;   // 4 fp32 acc

__device__ __forceinline__ unsigned short f2bf(float f) {   // RNE float->bf16
  unsigned int u = __float_as_uint(f);
  u += 0x7fffu + ((u >> 16) & 1u);
  return (unsigned short)(u >> 16);
}
__device__ __forceinline__ float bf2f(unsigned short h) {
  return __uint_as_float((unsigned int)h << 16);
}
// Two-regime erf (rel-accurate near 0 — required inside erf(x)/x):
__device__ __forceinline__ float fast_erf(float x) {
  float t2 = x * x;
  float small_v = 1.1283791671f * x *
      fmaf(t2, fmaf(t2, fmaf(t2, fmaf(t2, 4.6296296e-3f, -2.3809524e-2f),
                             0.1f), -0.33333333f), 1.0f);
  float t = __builtin_amdgcn_rcpf(fmaf(0.3275911f, x, 1.0f));
  float p = fmaf(fmaf(fmaf(fmaf(1.061405429f, t, -1.453152027f),
                           t, 1.421413741f), t, -0.284496736f), t, 0.254829592f);
  float big_v = fmaf(-p * t, __expf(-t2), 1.0f);
  return x < 0.5f ? small_v : big_v;
}
__device__ __forceinline__ float fast_tanh(float x) {      // rel err ~1e-6
  float ax = fabsf(x);
  float e = __expf(2.0f * ax);
  float t = 1.0f - 2.0f * __builtin_amdgcn_rcpf(e + 1.0f);
  return __builtin_copysignf(t, x);
}

// ------- chi MLP: 4 rows per wave, scalar(SGPR) feats, W1/W2 amortized -------
__global__ __launch_bounds__(256) void chi_kernel(
    const float* __restrict__ feats, const float* __restrict__ W1,
    const float* __restrict__ b1, const float* __restrict__ W2,
    const float* __restrict__ b2, const float* __restrict__ W3,
    const float* __restrict__ b3, float* __restrict__ chi)
{
  int wave = threadIdx.x >> 6, lane = threadIdx.x & 63;
  int row0 = __builtin_amdgcn_readfirstlane((blockIdx.x * 4 + wave) * 4);
  const float* f = feats + (size_t)row0 * DD;   // SGPR base -> s_load
  __shared__ float sh[4][4][UU];

  float a0 = b1[lane], a1 = a0, a2 = a0, a3 = a0;
  #pragma unroll 8
  for (int d = 0; d < DD; ++d) {
    float wv = W1[d * UU + lane];               // coalesced, L1-resident
    a0 = fmaf(f[d],          wv, a0);
    a1 = fmaf(f[DD + d],     wv, a1);
    a2 = fmaf(f[2 * DD + d], wv, a2);
    a3 = fmaf(f[3 * DD + d], wv, a3);
  }
  sh[wave][0][lane] = a0 - fast_tanh(a0);
  sh[wave][1][lane] = a1 - fast_tanh(a1);
  sh[wave][2][lane] = a2 - fast_tanh(a2);
  sh[wave][3][lane] = a3 - fast_tanh(a3);
  __builtin_amdgcn_s_waitcnt(0);                // lgkm drain before ds_read
  float c0 = b2[lane], c1 = c0, c2 = c0, c3 = c0;
  #pragma unroll 8
  for (int u = 0; u < UU; ++u) {
    float wv = W2[u * UU + lane];
    c0 = fmaf(sh[wave][0][u], wv, c0);          // LDS same-addr broadcast
    c1 = fmaf(sh[wave][1][u], wv, c1);
    c2 = fmaf(sh[wave][2][u], wv, c2);
    c3 = fmaf(sh[wave][3][u], wv, c3);
  }
  float w3 = W3[lane];
  float p0 = (c0 - fast_tanh(c0)) * w3;
  float p1 = (c1 - fast_tanh(c1)) * w3;
  float p2 = (c2 - fast_tanh(c2)) * w3;
  float p3 = (c3 - fast_tanh(c3)) * w3;
  #pragma unroll
  for (int off = 32; off; off >>= 1) {
    p0 += __shfl_down(p0, off, 64);
    p1 += __shfl_down(p1, off, 64);
    p2 += __shfl_down(p2, off, 64);
    p3 += __shfl_down(p3, off, 64);
  }
  if (lane == 0) {
    float bb = b3[0];
    float z0 = p0 + bb, z1 = p1 + bb, z2v = p2 + bb, z3 = p3 + bb;
    chi[row0]     = z0 - fast_tanh(z0);
    chi[row0 + 1] = z1 - fast_tanh(z1);
    chi[row0 + 2] = z2v - fast_tanh(z2v);
    chi[row0 + 3] = z3 - fast_tanh(z3);
  }
}

// ------ build A (fp32 coalesced to d_out) + bf16 frag-tile staged in LDS -----
// frag layout: (i,j) -> (i>>4)*8192 + (j>>5)*512 + ((j>>3)&3)*128 + (i&15)*8 + (j&7)
__global__ __launch_bounds__(256) void build_A_kernel(
    const float* __restrict__ pos, const int* __restrict__ ntype,
    const float* __restrict__ hardness, const float* __restrict__ sigma,
    float* __restrict__ Aout, unsigned short* __restrict__ Abf)
{
  int b = blockIdx.y;
  int r0 = blockIdx.x * 16;                  // exactly one 16-row frag tile
  __shared__ float px[NN], py[NN], pz[NN], s2[NN], hd[NN];
  __shared__ unsigned short tile[16 * NN];   // 16 KB frag-major bf16
  for (int n = threadIdx.x; n < NN; n += 256) {
    const float* p = pos + ((size_t)b * NN + n) * 3;
    px[n] = p[0]; py[n] = p[1]; pz[n] = p[2];
    int ty = ntype[b * NN + n];
    float s = sigma[ty];
    s2[n] = s * s;
    hd[n] = hardness[ty];
  }
  __syncthreads();
  int c0 = (threadIdx.x & 127) << 2;
  int rsub = threadIdx.x >> 7;
  float* outB = Aout + (size_t)b * NN * NN;
  for (int k = 0; k < 8; ++k) {
    int i = r0 + (k << 1) + rsub;
    float pxi = px[i], pyi = py[i], pzi = pz[i], s2i = s2[i];
    float4 v;
    float* vp = &v.x;
    #pragma unroll
    for (int c = 0; c < 4; ++c) {
      int j = c0 + c;
      float dx = pxi - px[j], dy = pyi - py[j], dz = pzi - pz[j];
      float d = sqrtf(fmaf(dx, dx, fmaf(dy, dy, dz * dz))) + NOISEF;
      float arg = d * __builtin_amdgcn_rsqf(2.0f * (s2i + s2[j]));
      float val = KCOUL * fast_erf(arg) * __builtin_amdgcn_rcpf(d);
      if (j == i) val += hd[i] + KCOUL * __builtin_amdgcn_rsqf(2.0f * M_PIF * s2i);
      vp[c] = val;
    }
    *reinterpret_cast<float4*>(outB + (size_t)i * NN + c0) = v;
    if (Abf) {
      ushort4 wv;
      wv.x = f2bf(v.x); wv.y = f2bf(v.y); wv.z = f2bf(v.z); wv.w = f2bf(v.w);
      int loc = ((c0 >> 5) << 9) + (((c0 >> 3) & 3) << 7) + ((i & 15) << 3) + (c0 & 7);
      *reinterpret_cast<ushort4*>(tile + loc) = wv;
    }
  }
  if (Abf) {
    __syncthreads();
    const uint4* src = reinterpret_cast<const uint4*>(tile);
    uint4* dst = reinterpret_cast<uint4*>(Abf + (size_t)b * NN * NN +
                                          ((size_t)(r0 >> 4) << 13));
    #pragma unroll
    for (int k = 0; k < 4; ++k)                 // 1024 uint4 = 16 KB coalesced
      dst[threadIdx.x + k * 256] = src[threadIdx.x + k * 256];
  }
}

// ------- Chronopoulos-Gear CG: A split LDS(9 strips) / L2-stream -------------
// Register-resident A is infeasible on this toolchain (rounds 1-4: allocator
// pins 64 VGPRs for 1024-thr blocks and spills the payload; WRITE_SIZE=16-24MB
// proved it).  Instead: 9 of 32 16-row strips (144 KB) live in LDS; the rest
// stream from L2 (368 KB/iter/CU vs 512 KB in round 0).  Per-XCD L2 working
// set 2.9 MB < 4 MB, so round-0's capacity-miss refetch also shrinks.
// wave w owns rows [32w,32w+32): lane holds (row=w*32+(lane>>1), rhs=lane&1).
// Waves 0..8 read their first 16-row tile from LDS (strip 2w staged at
// Alds+w*8192); second tile + waves 9..15 stream.
// r is stored as 4 bf16 planes {hi0,hi1,lo0,lo1}; B col = m&3 -> one MFMA
// covers hi+lo of both rhs; hi+lo combined by __shfl_xor(.,2).
constexpr int NSTRIP = 9;                  // strips resident in LDS (144 KB)

__global__ __launch_bounds__(1024) void cg_kernel_bf(
    const unsigned short* __restrict__ Abf, const float* __restrict__ tq,
    float* __restrict__ qout /* in: chi, out: charges */)
{
  int b = blockIdx.x;
  const unsigned short* A = Abf + (size_t)b * NN * NN;
  int t = threadIdx.x;
  int lane = t & 63, w = t >> 6;          // 16 waves
  constexpr int PADP = NN + 16;           // planes at banks 0/8/16/24
  __shared__ __align__(16) unsigned short Alds[NSTRIP * 8192];  // 144 KB
  __shared__ __align__(16) unsigned short rsp[4 * PADP];
  __shared__ float w01[2 * NN];           // [row*2 + rhs]
  __shared__ float4 wred[16];

  const int row = w * 32 + (lane >> 1);
  const int rhs = lane & 1;
  const int m  = lane & 15;               // D col index
  const int qd = lane >> 4;               // quad: k-subrange qd*8..+7
  const unsigned short* aw0 = A + ((size_t)(2 * w) << 13) + lane * 8;
  const unsigned short* aw1 = aw0 + 8192;
  const unsigned short* bp = rsp + (m & 3) * PADP + qd * 8;
  const unsigned short* als0 = Alds + w * 8192 + lane * 8;

  // ---- stage strips {2v : v<NSTRIP} into LDS, identity layout per strip ----
  // strip = 16 rows frag-major = 1024 uint4.  LDS u4 idx == linear idx; global
  // u4 idx = idx + v*1024 (strip 2v at global base (2v)*1024 u4).
  {
    const uint4* As4 = reinterpret_cast<const uint4*>(A);
    uint4* Ld4 = reinterpret_cast<uint4*>(Alds);
    #pragma unroll
    for (int k = 0; k < NSTRIP; ++k) {
      int idx = t + k * 1024;
      int v = idx >> 10;
      Ld4[idx] = As4[idx + (v << 10)];
    }
  }

  // ---- init: r = rhs (rhs0 = -chi, rhs1 = ones); x=p=q=0 ----
  float rv = rhs ? 1.0f : -qout[b * NN + row];
  float xv = 0.f, pv = 0.f, qv = 0.f;
  {
    unsigned short h = f2bf(rv);
    rsp[rhs * PADP + row] = h;                  // hi planes 0/1
    rsp[(2 + rhs) * PADP + row] = f2bf(rv - bf2f(h));  // lo planes 2/3
  }
  float rr = rv * rv;                      // parity-preserving reduce
  #pragma unroll
  for (int off = 2; off < 64; off <<= 1) rr += __shfl_down(rr, off, 64);
  if (lane < 2) reinterpret_cast<float2*>(&wred[w])[lane] = make_float2(rr, 0.f);
  __syncthreads();
  float mu0 = 0.f, mu1 = 0.f;
  #pragma unroll
  for (int g = 0; g < 16; ++g) { mu0 += wred[g].x; mu1 += wred[g].z; }
  float tol0 = fmaxf(1e-4f * mu0, 1e-12f);   // rel residual 1e-2
  float tol1 = fmaxf(1e-4f * mu1, 1e-12f);
  bool act0 = mu0 > tol0, act1 = mu1 > tol1;
  __syncthreads();                         // protect wred before iter-0 rewrite

  float muold0 = 1.f, muold1 = 1.f, alold0 = 1.f, alold1 = 1.f;
  for (int k = 0; k < 24 && (act0 || act1); ++k) {
    // ---- matvec: tile0 from LDS (w<NSTRIP) else L2; tile1 from L2 ----
    ffrag acc0 = {0.f, 0.f, 0.f, 0.f};
    ffrag acc1 = {0.f, 0.f, 0.f, 0.f};
#define STEP(c, S0, S1) { \
    bfrag bv = *reinterpret_cast<const bfrag*>(bp + (c) * 32); \
    bfrag a0v = *reinterpret_cast<const bfrag*>(S0 + (c) * 512); \
    bfrag a1v = *reinterpret_cast<const bfrag*>(S1 + (c) * 512); \
    acc0 = __builtin_amdgcn_mfma_f32_16x16x32_bf16(a0v, bv, acc0, 0, 0, 0); \
    acc1 = __builtin_amdgcn_mfma_f32_16x16x32_bf16(a1v, bv, acc1, 0, 0, 0); }
    if (w < NSTRIP) {
      STEP(0, als0, aw1) STEP(1, als0, aw1) STEP(2, als0, aw1) STEP(3, als0, aw1)
      STEP(4, als0, aw1) STEP(5, als0, aw1) STEP(6, als0, aw1) STEP(7, als0, aw1)
      STEP(8, als0, aw1) STEP(9, als0, aw1) STEP(10, als0, aw1) STEP(11, als0, aw1)
      STEP(12, als0, aw1) STEP(13, als0, aw1) STEP(14, als0, aw1) STEP(15, als0, aw1)
    } else {
      STEP(0, aw0, aw1) STEP(1, aw0, aw1) STEP(2, aw0, aw1) STEP(3, aw0, aw1)
      STEP(4, aw0, aw1) STEP(5, aw0, aw1) STEP(6, aw0, aw1) STEP(7, aw0, aw1)
      STEP(8, aw0, aw1) STEP(9, aw0, aw1) STEP(10, aw0, aw1) STEP(11, aw0, aw1)
      STEP(12, aw0, aw1) STEP(13, aw0, aw1) STEP(14, aw0, aw1) STEP(15, aw0, aw1)
    }
#undef STEP
    // combine hi(cols m) + lo(cols m^2): every lane then holds w for rhs=m&1
    #pragma unroll
    for (int r = 0; r < 4; ++r) {
      acc0[r] += __shfl_xor(acc0[r], 2, 64);
      acc1[r] += __shfl_xor(acc1[r], 2, 64);
    }
    // D: col=lane&15 (rhs), row-in-tile = qd*4+reg.  Own-strip write:
    if (m < 2) {
      int rbase = qd * 4;
      #pragma unroll
      for (int r = 0; r < 4; ++r) {
        w01[(w * 32 + rbase + r) * 2 + m]      = acc0[r];
        w01[(w * 32 + 16 + rbase + r) * 2 + m] = acc1[r];
      }
    }
    float wv = w01[row * 2 + rhs];         // same-wave LDS round trip (no barrier)

    // ---- per-wave dot partials (mu=r.r, nu=r.w), parity-preserving ----
    float pr = rv * rv, pw = rv * wv;
    #pragma unroll
    for (int off = 2; off < 64; off <<= 1) {
      pr += __shfl_down(pr, off, 64);
      pw += __shfl_down(pw, off, 64);
    }
    if (lane < 2) reinterpret_cast<float2*>(&wred[w])[lane] = make_float2(pr, pw);
    __syncthreads();                       // BARRIER A

    float s0 = 0.f, n0 = 0.f, s1 = 0.f, n1 = 0.f;
    #pragma unroll
    for (int g = 0; g < 16; ++g) {
      float4 u = wred[g];
      s0 += u.x; n0 += u.y; s1 += u.z; n1 += u.w;
    }
    if (act0 && s0 <= tol0) act0 = false;
    if (act1 && s1 <= tol1) act1 = false;
    if (!act0 && !act1) break;             // uniform decision
    float be0 = 0.f, al0 = 0.f, be1 = 0.f, al1 = 0.f;
    if (act0) {
      be0 = k ? s0 / muold0 : 0.f;
      al0 = s0 / (n0 - be0 * s0 / alold0);
      muold0 = s0; alold0 = al0;
    }
    if (act1) {
      be1 = k ? s1 / muold1 : 0.f;
      al1 = s1 / (n1 - be1 * s1 / alold1);
      muold1 = s1; alold1 = al1;
    }
    float be = rhs ? be1 : be0;
    float al = rhs ? al1 : al0;

    // ---- register vector phase + bf16 hi/lo split of new r ----
    pv = fmaf(be, pv, rv);
    qv = fmaf(be, qv, wv);
    xv = fmaf(al, pv, xv);
    rv = fmaf(-al, qv, rv);
    unsigned short h = f2bf(rv);
    rsp[rhs * PADP + row] = h;
    rsp[(2 + rhs) * PADP + row] = f2bf(rv - bf2f(h));
    __syncthreads();                       // BARRIER B
  }

  // ---- epilogue: lambda = (1'y - Q)/(1'z); charges = y - lambda*z ----
  __syncthreads();                         // all done reading wred
  float sx = xv;
  #pragma unroll
  for (int off = 2; off < 64; off <<= 1) sx += __shfl_down(sx, off, 64);
  if (lane < 2) reinterpret_cast<float2*>(&wred[w])[lane] = make_float2(sx, 0.f);
  __syncthreads();
  float sum0 = 0.f, sum1 = 0.f;
  #pragma unroll
  for (int g = 0; g < 16; ++g) { sum0 += wred[g].x; sum1 += wred[g].z; }
  float lam = (sum0 - tq[b]) / sum1;
  float xpart = __shfl_xor(xv, 1, 64);     // partner's x (other rhs)
  if (rhs == 0) qout[b * NN + row] = xv - lam * xpart;
}

// ---------------- fp32 fallback (round-3 structure) --------------------------
__device__ __forceinline__ float2 blockReduce2(float2 v, float2* wred, int t) {
  #pragma unroll
  for (int off = 32; off; off >>= 1) {
    v.x += __shfl_down(v.x, off, 64);
    v.y += __shfl_down(v.y, off, 64);
  }
  __syncthreads();
  if ((t & 63) == 0) wred[t >> 6] = v;
  __syncthreads();
  float2 r = wred[0];
  #pragma unroll
  for (int k = 1; k < 16; ++k) { r.x += wred[k].x; r.y += wred[k].y; }
  return r;
}

__global__ __launch_bounds__(1024) void cg_kernel_f32(
    const float* __restrict__ Aall, const float* __restrict__ tq,
    float* __restrict__ qout)
{
  int b = blockIdx.x;
  const float* A = Aall + (size_t)b * NN * NN;
  int t = threadIdx.x;
  __shared__ float2 p01[NN], q01[NN], r01[NN], x01[NN];
  __shared__ float4 sacc0[8][128];
  __shared__ float4 sacc1[8][128];
  __shared__ float2 wred[16];

  float2 z2 = make_float2(0.f, 0.f);
  float2 rsq = z2;
  if (t < NN) {
    float b0 = -qout[b * NN + t];
    x01[t] = z2;
    r01[t] = make_float2(b0, 1.0f);
    p01[t] = make_float2(b0, 1.0f);
    rsq = make_float2(b0 * b0, 1.0f);
  }
  float2 rr = blockReduce2(rsq, wred, t);
  float tol0 = fmaxf(1e-4f * rr.x, 1e-12f);
  float tol1 = fmaxf(1e-4f * rr.y, 1e-12f);
  const int c4 = (t & 127) << 2;
  const int jr = t >> 7;
  for (int it = 0; it < 24; ++it) {
    bool act0 = rr.x > tol0, act1 = rr.y > tol1;
    if (!act0 && !act1) break;
    {
      const float* ap = A + (size_t)(jr * 64) * NN + c4;
      float4 a0 = make_float4(0.f, 0.f, 0.f, 0.f);
      float4 a1 = a0;
      #pragma unroll 8
      for (int mI = 0; mI < 64; ++mI) {
        float4 av = *reinterpret_cast<const float4*>(ap);
        ap += NN;
        float2 pj = p01[jr * 64 + mI];
        a0.x = fmaf(av.x, pj.x, a0.x); a0.y = fmaf(av.y, pj.x, a0.y);
        a0.z = fmaf(av.z, pj.x, a0.z); a0.w = fmaf(av.w, pj.x, a0.w);
        a1.x = fmaf(av.x, pj.y, a1.x); a1.y = fmaf(av.y, pj.y, a1.y);
        a1.z = fmaf(av.z, pj.y, a1.z); a1.w = fmaf(av.w, pj.y, a1.w);
      }
      sacc0[jr][t & 127] = a0;
      sacc1[jr][t & 127] = a1;
    }
    __syncthreads();
    float2 dv = z2;
    if (t < NN) {
      const float* f0 = reinterpret_cast<const float*>(sacc0);
      const float* f1 = reinterpret_cast<const float*>(sacc1);
      float s0 = 0.f, s1 = 0.f;
      #pragma unroll
      for (int g = 0; g < 8; ++g) { s0 += f0[g * 512 + t]; s1 += f1[g * 512 + t]; }
      q01[t] = make_float2(s0, s1);
      float2 pv = p01[t];
      dv.x = s0 * pv.x; dv.y = s1 * pv.y;
    }
    float2 pq = blockReduce2(dv, wred, t);
    float al0 = act0 ? rr.x / pq.x : 0.f;
    float al1 = act1 ? rr.y / pq.y : 0.f;
    float2 rn = z2;
    if (t < NN) {
      float2 xv = x01[t], rv = r01[t], pv = p01[t], qv = q01[t];
      xv.x = fmaf(al0, pv.x, xv.x);  xv.y = fmaf(al1, pv.y, xv.y);
      rv.x = fmaf(-al0, qv.x, rv.x); rv.y = fmaf(-al1, qv.y, rv.y);
      x01[t] = xv; r01[t] = rv;
      rn.x = rv.x * rv.x; rn.y = rv.y * rv.y;
    }
    float2 rrn = blockReduce2(rn, wred, t);
    float be0 = act0 ? rrn.x / rr.x : 0.f;
    float be1 = act1 ? rrn.y / rr.y : 0.f;
    if (t < NN) {
      float2 rv = r01[t], pv = p01[t];
      pv.x = fmaf(be0, pv.x, rv.x);
      pv.y = fmaf(be1, pv.y, rv.y);
      p01[t] = pv;
    }
    rr = rrn;
    __syncthreads();
  }
  float2 sv = z2;
  if (t < NN) sv = x01[t];
  float2 s = blockReduce2(sv, wred, t);
  float lam = (s.x - tq[b]) / s.y;
  if (t < NN) qout[b * NN + t] = x01[t].x - lam * x01[t].y;
}

extern "C" void kernel_launch(void* const* d_in, const int* in_sizes, int n_in,
                              void* d_out, int out_size, void* d_ws, size_t ws_size,
                              hipStream_t stream) {
  const float* pos      = (const float*)d_in[0];
  const float* feats    = (const float*)d_in[1];
  const int*   ntype    = (const int*)  d_in[2];
  const float* tq       = (const float*)d_in[3];
  const float* hardness = (const float*)d_in[4];
  const float* sigma    = (const float*)d_in[5];
  const float* W1 = (const float*)d_in[6];
  const float* b1 = (const float*)d_in[7];
  const float* W2 = (const float*)d_in[8];
  const float* b2 = (const float*)d_in[9];
  const float* W3 = (const float*)d_in[10];
  const float* b3 = (const float*)d_in[11];

  float* out  = (float*)d_out;
  float* chi  = out;             // charges region doubles as chi scratch
  float* Aout = out + BB * NN;   // output 1: A, batch-major

  const size_t bf_bytes = (size_t)BB * NN * NN * sizeof(unsigned short);
  const bool use_bf = ws_size >= bf_bytes;
  unsigned short* Abf = use_bf ? (unsigned short*)d_ws : nullptr;

  chi_kernel<<<dim3(BB * NN / 16), dim3(256), 0, stream>>>(feats, W1, b1, W2, b2, W3, b3, chi);
  build_A_kernel<<<dim3(NN / 16, BB), dim3(256), 0, stream>>>(pos, ntype, hardness, sigma, Aout, Abf);
  if (use_bf)
    cg_kernel_bf<<<dim3(BB), dim3(1024), 0, stream>>>(Abf, tq, chi);
  else
    cg_kernel_f32<<<dim3(BB), dim3(1024), 0, stream>>>(Aout, tq, chi);
}

// Round 6
// 229.022 us; speedup vs baseline: 1.4129x; 1.4129x over previous
//
#include <hip/hip_runtime.h>
#include <math.h>

constexpr int BB = 64, NN = 512, DD = 128, UU = 64;
constexpr float KCOUL = 14.399645351950548f;
constexpr float NOISEF = 1e-8f;
#define M_PIF 3.14159265358979323846f

typedef __attribute__((ext_vector_type(8))) short bfrag;   // 8 bf16 (4 VGPRs)
typedef __attribute__((ext_vector_type(4))) float ffrag;   // 4 fp32 acc

__device__ __forceinline__ unsigned short f2bf(float f) {   // RNE float->bf16
  unsigned int u = __float_as_uint(f);
  u += 0x7fffu + ((u >> 16) & 1u);
  return (unsigned short)(u >> 16);
}
__device__ __forceinline__ float bf2f(unsigned short h) {
  return __uint_as_float((unsigned int)h << 16);
}
// Two-regime erf (rel-accurate near 0 — required inside erf(x)/x):
__device__ __forceinline__ float fast_erf(float x) {
  float t2 = x * x;
  float small_v = 1.1283791671f * x *
      fmaf(t2, fmaf(t2, fmaf(t2, fmaf(t2, 4.6296296e-3f, -2.3809524e-2f),
                             0.1f), -0.33333333f), 1.0f);
  float t = __builtin_amdgcn_rcpf(fmaf(0.3275911f, x, 1.0f));
  float p = fmaf(fmaf(fmaf(fmaf(1.061405429f, t, -1.453152027f),
                           t, 1.421413741f), t, -0.284496736f), t, 0.254829592f);
  float big_v = fmaf(-p * t, __expf(-t2), 1.0f);
  return x < 0.5f ? small_v : big_v;
}
__device__ __forceinline__ float fast_tanh(float x) {      // rel err ~1e-6
  float ax = fabsf(x);
  float e = __expf(2.0f * ax);
  float t = 1.0f - 2.0f * __builtin_amdgcn_rcpf(e + 1.0f);
  return __builtin_copysignf(t, x);
}

// ------- chi MLP: 4 rows per wave, scalar(SGPR) feats, W1/W2 amortized -------
__global__ __launch_bounds__(256) void chi_kernel(
    const float* __restrict__ feats, const float* __restrict__ W1,
    const float* __restrict__ b1, const float* __restrict__ W2,
    const float* __restrict__ b2, const float* __restrict__ W3,
    const float* __restrict__ b3, float* __restrict__ chi)
{
  int wave = threadIdx.x >> 6, lane = threadIdx.x & 63;
  int row0 = __builtin_amdgcn_readfirstlane((blockIdx.x * 4 + wave) * 4);
  const float* f = feats + (size_t)row0 * DD;   // SGPR base -> s_load
  __shared__ float sh[4][4][UU];

  float a0 = b1[lane], a1 = a0, a2 = a0, a3 = a0;
  #pragma unroll 8
  for (int d = 0; d < DD; ++d) {
    float wv = W1[d * UU + lane];               // coalesced, L1-resident
    a0 = fmaf(f[d],          wv, a0);
    a1 = fmaf(f[DD + d],     wv, a1);
    a2 = fmaf(f[2 * DD + d], wv, a2);
    a3 = fmaf(f[3 * DD + d], wv, a3);
  }
  sh[wave][0][lane] = a0 - fast_tanh(a0);
  sh[wave][1][lane] = a1 - fast_tanh(a1);
  sh[wave][2][lane] = a2 - fast_tanh(a2);
  sh[wave][3][lane] = a3 - fast_tanh(a3);
  __builtin_amdgcn_s_waitcnt(0);                // lgkm drain before ds_read
  float c0 = b2[lane], c1 = c0, c2 = c0, c3 = c0;
  #pragma unroll 8
  for (int u = 0; u < UU; ++u) {
    float wv = W2[u * UU + lane];
    c0 = fmaf(sh[wave][0][u], wv, c0);          // LDS same-addr broadcast
    c1 = fmaf(sh[wave][1][u], wv, c1);
    c2 = fmaf(sh[wave][2][u], wv, c2);
    c3 = fmaf(sh[wave][3][u], wv, c3);
  }
  float w3 = W3[lane];
  float p0 = (c0 - fast_tanh(c0)) * w3;
  float p1 = (c1 - fast_tanh(c1)) * w3;
  float p2 = (c2 - fast_tanh(c2)) * w3;
  float p3 = (c3 - fast_tanh(c3)) * w3;
  #pragma unroll
  for (int off = 32; off; off >>= 1) {
    p0 += __shfl_down(p0, off, 64);
    p1 += __shfl_down(p1, off, 64);
    p2 += __shfl_down(p2, off, 64);
    p3 += __shfl_down(p3, off, 64);
  }
  if (lane == 0) {
    float bb = b3[0];
    float z0 = p0 + bb, z1 = p1 + bb, z2v = p2 + bb, z3 = p3 + bb;
    chi[row0]     = z0 - fast_tanh(z0);
    chi[row0 + 1] = z1 - fast_tanh(z1);
    chi[row0 + 2] = z2v - fast_tanh(z2v);
    chi[row0 + 3] = z3 - fast_tanh(z3);
  }
}

// ------ build A (fp32 coalesced to d_out) + bf16 frag-tile staged in LDS -----
// frag layout: (i,j) -> (i>>4)*8192 + (j>>5)*512 + ((j>>3)&3)*128 + (i&15)*8 + (j&7)
__global__ __launch_bounds__(256) void build_A_kernel(
    const float* __restrict__ pos, const int* __restrict__ ntype,
    const float* __restrict__ hardness, const float* __restrict__ sigma,
    float* __restrict__ Aout, unsigned short* __restrict__ Abf)
{
  int b = blockIdx.y;
  int r0 = blockIdx.x * 16;                  // exactly one 16-row frag tile
  __shared__ float px[NN], py[NN], pz[NN], s2[NN], hd[NN];
  __shared__ unsigned short tile[16 * NN];   // 16 KB frag-major bf16
  for (int n = threadIdx.x; n < NN; n += 256) {
    const float* p = pos + ((size_t)b * NN + n) * 3;
    px[n] = p[0]; py[n] = p[1]; pz[n] = p[2];
    int ty = ntype[b * NN + n];
    float s = sigma[ty];
    s2[n] = s * s;
    hd[n] = hardness[ty];
  }
  __syncthreads();
  int c0 = (threadIdx.x & 127) << 2;
  int rsub = threadIdx.x >> 7;
  float* outB = Aout + (size_t)b * NN * NN;
  for (int k = 0; k < 8; ++k) {
    int i = r0 + (k << 1) + rsub;
    float pxi = px[i], pyi = py[i], pzi = pz[i], s2i = s2[i];
    float4 v;
    float* vp = &v.x;
    #pragma unroll
    for (int c = 0; c < 4; ++c) {
      int j = c0 + c;
      float dx = pxi - px[j], dy = pyi - py[j], dz = pzi - pz[j];
      float d = sqrtf(fmaf(dx, dx, fmaf(dy, dy, dz * dz))) + NOISEF;
      float arg = d * __builtin_amdgcn_rsqf(2.0f * (s2i + s2[j]));
      float val = KCOUL * fast_erf(arg) * __builtin_amdgcn_rcpf(d);
      if (j == i) val += hd[i] + KCOUL * __builtin_amdgcn_rsqf(2.0f * M_PIF * s2i);
      vp[c] = val;
    }
    *reinterpret_cast<float4*>(outB + (size_t)i * NN + c0) = v;
    if (Abf) {
      ushort4 wv;
      wv.x = f2bf(v.x); wv.y = f2bf(v.y); wv.z = f2bf(v.z); wv.w = f2bf(v.w);
      int loc = ((c0 >> 5) << 9) + (((c0 >> 3) & 3) << 7) + ((i & 15) << 3) + (c0 & 7);
      *reinterpret_cast<ushort4*>(tile + loc) = wv;
    }
  }
  if (Abf) {
    __syncthreads();
    const uint4* src = reinterpret_cast<const uint4*>(tile);
    uint4* dst = reinterpret_cast<uint4*>(Abf + (size_t)b * NN * NN +
                                          ((size_t)(r0 >> 4) << 13));
    #pragma unroll
    for (int k = 0; k < 4; ++k)                 // 1024 uint4 = 16 KB coalesced
      dst[threadIdx.x + k * 256] = src[threadIdx.x + k * 256];
  }
}

// ------- Chronopoulos-Gear CG: A split LDS(9 strips) / L2-stream -------------
// Same structure as round 5 (correctness-verified) with ONE change: the matvec
// c-loop is back to round-0's `#pragma unroll 4` + small body.  Round 5's
// manual 16x unroll let the scheduler hoist ~48 loads -> past the 64-VGPR cap
// -> spill (WRITE 9.6 MB) -> 8 MB/XCD scratch working set thrashed L2
// (FETCH 86.6 MB).  unroll 4 keeps <=12 loads in flight (round 0: 52 VGPR,
// no spill at the same shape).
// wave w owns rows [32w,32w+32): lane holds (row=w*32+(lane>>1), rhs=lane&1).
// Waves 0..8 read their first 16-row tile from LDS (144 KB staged once);
// second tile + waves 9..15 stream from L2 (368 KB/iter/CU vs 512 in rnd 0).
// r is stored as 4 bf16 planes {hi0,hi1,lo0,lo1}; B col = m&3 -> one MFMA
// covers hi+lo of both rhs; hi+lo combined by __shfl_xor(.,2).
constexpr int NSTRIP = 9;                  // strips resident in LDS (144 KB)

__global__ __launch_bounds__(1024) void cg_kernel_bf(
    const unsigned short* __restrict__ Abf, const float* __restrict__ tq,
    float* __restrict__ qout /* in: chi, out: charges */)
{
  int b = blockIdx.x;
  const unsigned short* A = Abf + (size_t)b * NN * NN;
  int t = threadIdx.x;
  int lane = t & 63, w = t >> 6;          // 16 waves
  constexpr int PADP = NN + 16;           // planes at banks 0/8/16/24
  __shared__ __align__(16) unsigned short Alds[NSTRIP * 8192];  // 144 KB
  __shared__ __align__(16) unsigned short rsp[4 * PADP];
  __shared__ float w01[2 * NN];           // [row*2 + rhs]
  __shared__ float4 wred[16];

  const int row = w * 32 + (lane >> 1);
  const int rhs = lane & 1;
  const int m  = lane & 15;               // D col index
  const int qd = lane >> 4;               // quad: k-subrange qd*8..+7
  const unsigned short* aw0 = A + ((size_t)(2 * w) << 13) + lane * 8;
  const unsigned short* aw1 = aw0 + 8192;
  const unsigned short* bp = rsp + (m & 3) * PADP + qd * 8;
  const unsigned short* als0 = Alds + w * 8192 + lane * 8;

  // ---- stage strips {2v : v<NSTRIP} into LDS, identity layout per strip ----
  {
    const uint4* As4 = reinterpret_cast<const uint4*>(A);
    uint4* Ld4 = reinterpret_cast<uint4*>(Alds);
    #pragma unroll
    for (int k = 0; k < NSTRIP; ++k) {
      int idx = t + k * 1024;
      int v = idx >> 10;
      Ld4[idx] = As4[idx + (v << 10)];
    }
  }

  // ---- init: r = rhs (rhs0 = -chi, rhs1 = ones); x=p=q=0 ----
  float rv = rhs ? 1.0f : -qout[b * NN + row];
  float xv = 0.f, pv = 0.f, qv = 0.f;
  {
    unsigned short h = f2bf(rv);
    rsp[rhs * PADP + row] = h;                  // hi planes 0/1
    rsp[(2 + rhs) * PADP + row] = f2bf(rv - bf2f(h));  // lo planes 2/3
  }
  float rr = rv * rv;                      // parity-preserving reduce
  #pragma unroll
  for (int off = 2; off < 64; off <<= 1) rr += __shfl_down(rr, off, 64);
  if (lane < 2) reinterpret_cast<float2*>(&wred[w])[lane] = make_float2(rr, 0.f);
  __syncthreads();
  float mu0 = 0.f, mu1 = 0.f;
  #pragma unroll
  for (int g = 0; g < 16; ++g) { mu0 += wred[g].x; mu1 += wred[g].z; }
  float tol0 = fmaxf(1e-4f * mu0, 1e-12f);   // rel residual 1e-2
  float tol1 = fmaxf(1e-4f * mu1, 1e-12f);
  bool act0 = mu0 > tol0, act1 = mu1 > tol1;
  __syncthreads();                         // protect wred before iter-0 rewrite

  float muold0 = 1.f, muold1 = 1.f, alold0 = 1.f, alold1 = 1.f;
  for (int k = 0; k < 24 && (act0 || act1); ++k) {
    // ---- matvec: tile0 from LDS (w<NSTRIP) else L2; tile1 from L2 ----
    // Round-0 loop shape (unroll 4, small body) -> no spill.
    ffrag acc0 = {0.f, 0.f, 0.f, 0.f};
    ffrag acc1 = {0.f, 0.f, 0.f, 0.f};
    if (w < NSTRIP) {
      #pragma unroll 4
      for (int c = 0; c < 16; ++c) {
        bfrag bv  = *reinterpret_cast<const bfrag*>(bp + c * 32);
        bfrag a0v = *reinterpret_cast<const bfrag*>(als0 + c * 512);
        bfrag a1v = *reinterpret_cast<const bfrag*>(aw1 + c * 512);
        acc0 = __builtin_amdgcn_mfma_f32_16x16x32_bf16(a0v, bv, acc0, 0, 0, 0);
        acc1 = __builtin_amdgcn_mfma_f32_16x16x32_bf16(a1v, bv, acc1, 0, 0, 0);
      }
    } else {
      #pragma unroll 4
      for (int c = 0; c < 16; ++c) {
        bfrag bv  = *reinterpret_cast<const bfrag*>(bp + c * 32);
        bfrag a0v = *reinterpret_cast<const bfrag*>(aw0 + c * 512);
        bfrag a1v = *reinterpret_cast<const bfrag*>(aw1 + c * 512);
        acc0 = __builtin_amdgcn_mfma_f32_16x16x32_bf16(a0v, bv, acc0, 0, 0, 0);
        acc1 = __builtin_amdgcn_mfma_f32_16x16x32_bf16(a1v, bv, acc1, 0, 0, 0);
      }
    }
    // combine hi(cols m) + lo(cols m^2): every lane then holds w for rhs=m&1
    #pragma unroll
    for (int r = 0; r < 4; ++r) {
      acc0[r] += __shfl_xor(acc0[r], 2, 64);
      acc1[r] += __shfl_xor(acc1[r], 2, 64);
    }
    // D: col=lane&15 (rhs), row-in-tile = qd*4+reg.  Own-strip write:
    if (m < 2) {
      int rbase = qd * 4;
      #pragma unroll
      for (int r = 0; r < 4; ++r) {
        w01[(w * 32 + rbase + r) * 2 + m]      = acc0[r];
        w01[(w * 32 + 16 + rbase + r) * 2 + m] = acc1[r];
      }
    }
    float wv = w01[row * 2 + rhs];         // same-wave LDS round trip (no barrier)

    // ---- per-wave dot partials (mu=r.r, nu=r.w), parity-preserving ----
    float pr = rv * rv, pw = rv * wv;
    #pragma unroll
    for (int off = 2; off < 64; off <<= 1) {
      pr += __shfl_down(pr, off, 64);
      pw += __shfl_down(pw, off, 64);
    }
    if (lane < 2) reinterpret_cast<float2*>(&wred[w])[lane] = make_float2(pr, pw);
    __syncthreads();                       // BARRIER A

    float s0 = 0.f, n0 = 0.f, s1 = 0.f, n1 = 0.f;
    #pragma unroll
    for (int g = 0; g < 16; ++g) {
      float4 u = wred[g];
      s0 += u.x; n0 += u.y; s1 += u.z; n1 += u.w;
    }
    if (act0 && s0 <= tol0) act0 = false;
    if (act1 && s1 <= tol1) act1 = false;
    if (!act0 && !act1) break;             // uniform decision
    float be0 = 0.f, al0 = 0.f, be1 = 0.f, al1 = 0.f;
    if (act0) {
      be0 = k ? s0 / muold0 : 0.f;
      al0 = s0 / (n0 - be0 * s0 / alold0);
      muold0 = s0; alold0 = al0;
    }
    if (act1) {
      be1 = k ? s1 / muold1 : 0.f;
      al1 = s1 / (n1 - be1 * s1 / alold1);
      muold1 = s1; alold1 = al1;
    }
    float be = rhs ? be1 : be0;
    float al = rhs ? al1 : al0;

    // ---- register vector phase + bf16 hi/lo split of new r ----
    pv = fmaf(be, pv, rv);
    qv = fmaf(be, qv, wv);
    xv = fmaf(al, pv, xv);
    rv = fmaf(-al, qv, rv);
    unsigned short h = f2bf(rv);
    rsp[rhs * PADP + row] = h;
    rsp[(2 + rhs) * PADP + row] = f2bf(rv - bf2f(h));
    __syncthreads();                       // BARRIER B
  }

  // ---- epilogue: lambda = (1'y - Q)/(1'z); charges = y - lambda*z ----
  __syncthreads();                         // all done reading wred
  float sx = xv;
  #pragma unroll
  for (int off = 2; off < 64; off <<= 1) sx += __shfl_down(sx, off, 64);
  if (lane < 2) reinterpret_cast<float2*>(&wred[w])[lane] = make_float2(sx, 0.f);
  __syncthreads();
  float sum0 = 0.f, sum1 = 0.f;
  #pragma unroll
  for (int g = 0; g < 16; ++g) { sum0 += wred[g].x; sum1 += wred[g].z; }
  float lam = (sum0 - tq[b]) / sum1;
  float xpart = __shfl_xor(xv, 1, 64);     // partner's x (other rhs)
  if (rhs == 0) qout[b * NN + row] = xv - lam * xpart;
}

// ---------------- fp32 fallback (round-3 structure) --------------------------
__device__ __forceinline__ float2 blockReduce2(float2 v, float2* wred, int t) {
  #pragma unroll
  for (int off = 32; off; off >>= 1) {
    v.x += __shfl_down(v.x, off, 64);
    v.y += __shfl_down(v.y, off, 64);
  }
  __syncthreads();
  if ((t & 63) == 0) wred[t >> 6] = v;
  __syncthreads();
  float2 r = wred[0];
  #pragma unroll
  for (int k = 1; k < 16; ++k) { r.x += wred[k].x; r.y += wred[k].y; }
  return r;
}

__global__ __launch_bounds__(1024) void cg_kernel_f32(
    const float* __restrict__ Aall, const float* __restrict__ tq,
    float* __restrict__ qout)
{
  int b = blockIdx.x;
  const float* A = Aall + (size_t)b * NN * NN;
  int t = threadIdx.x;
  __shared__ float2 p01[NN], q01[NN], r01[NN], x01[NN];
  __shared__ float4 sacc0[8][128];
  __shared__ float4 sacc1[8][128];
  __shared__ float2 wred[16];

  float2 z2 = make_float2(0.f, 0.f);
  float2 rsq = z2;
  if (t < NN) {
    float b0 = -qout[b * NN + t];
    x01[t] = z2;
    r01[t] = make_float2(b0, 1.0f);
    p01[t] = make_float2(b0, 1.0f);
    rsq = make_float2(b0 * b0, 1.0f);
  }
  float2 rr = blockReduce2(rsq, wred, t);
  float tol0 = fmaxf(1e-4f * rr.x, 1e-12f);
  float tol1 = fmaxf(1e-4f * rr.y, 1e-12f);
  const int c4 = (t & 127) << 2;
  const int jr = t >> 7;
  for (int it = 0; it < 24; ++it) {
    bool act0 = rr.x > tol0, act1 = rr.y > tol1;
    if (!act0 && !act1) break;
    {
      const float* ap = A + (size_t)(jr * 64) * NN + c4;
      float4 a0 = make_float4(0.f, 0.f, 0.f, 0.f);
      float4 a1 = a0;
      #pragma unroll 8
      for (int mI = 0; mI < 64; ++mI) {
        float4 av = *reinterpret_cast<const float4*>(ap);
        ap += NN;
        float2 pj = p01[jr * 64 + mI];
        a0.x = fmaf(av.x, pj.x, a0.x); a0.y = fmaf(av.y, pj.x, a0.y);
        a0.z = fmaf(av.z, pj.x, a0.z); a0.w = fmaf(av.w, pj.x, a0.w);
        a1.x = fmaf(av.x, pj.y, a1.x); a1.y = fmaf(av.y, pj.y, a1.y);
        a1.z = fmaf(av.z, pj.y, a1.z); a1.w = fmaf(av.w, pj.y, a1.w);
      }
      sacc0[jr][t & 127] = a0;
      sacc1[jr][t & 127] = a1;
    }
    __syncthreads();
    float2 dv = z2;
    if (t < NN) {
      const float* f0 = reinterpret_cast<const float*>(sacc0);
      const float* f1 = reinterpret_cast<const float*>(sacc1);
      float s0 = 0.f, s1 = 0.f;
      #pragma unroll
      for (int g = 0; g < 8; ++g) { s0 += f0[g * 512 + t]; s1 += f1[g * 512 + t]; }
      q01[t] = make_float2(s0, s1);
      float2 pv = p01[t];
      dv.x = s0 * pv.x; dv.y = s1 * pv.y;
    }
    float2 pq = blockReduce2(dv, wred, t);
    float al0 = act0 ? rr.x / pq.x : 0.f;
    float al1 = act1 ? rr.y / pq.y : 0.f;
    float2 rn = z2;
    if (t < NN) {
      float2 xv = x01[t], rv = r01[t], pv = p01[t], qv = q01[t];
      xv.x = fmaf(al0, pv.x, xv.x);  xv.y = fmaf(al1, pv.y, xv.y);
      rv.x = fmaf(-al0, qv.x, rv.x); rv.y = fmaf(-al1, qv.y, rv.y);
      x01[t] = xv; r01[t] = rv;
      rn.x = rv.x * rv.x; rn.y = rv.y * rv.y;
    }
    float2 rrn = blockReduce2(rn, wred, t);
    float be0 = act0 ? rrn.x / rr.x : 0.f;
    float be1 = act1 ? rrn.y / rr.y : 0.f;
    if (t < NN) {
      float2 rv = r01[t], pv = p01[t];
      pv.x = fmaf(be0, pv.x, rv.x);
      pv.y = fmaf(be1, pv.y, rv.y);
      p01[t] = pv;
    }
    rr = rrn;
    __syncthreads();
  }
  float2 sv = z2;
  if (t < NN) sv = x01[t];
  float2 s = blockReduce2(sv, wred, t);
  float lam = (s.x - tq[b]) / s.y;
  if (t < NN) qout[b * NN + t] = x01[t].x - lam * x01[t].y;
}

extern "C" void kernel_launch(void* const* d_in, const int* in_sizes, int n_in,
                              void* d_out, int out_size, void* d_ws, size_t ws_size,
                              hipStream_t stream) {
  const float* pos      = (const float*)d_in[0];
  const float* feats    = (const float*)d_in[1];
  const int*   ntype    = (const int*)  d_in[2];
  const float* tq       = (const float*)d_in[3];
  const float* hardness = (const float*)d_in[4];
  const float* sigma    = (const float*)d_in[5];
  const float* W1 = (const float*)d_in[6];
  const float* b1 = (const float*)d_in[7];
  const float* W2 = (const float*)d_in[8];
  const float* b2 = (const float*)d_in[9];
  const float* W3 = (const float*)d_in[10];
  const float* b3 = (const float*)d_in[11];

  float* out  = (float*)d_out;
  float* chi  = out;             // charges region doubles as chi scratch
  float* Aout = out + BB * NN;   // output 1: A, batch-major

  const size_t bf_bytes = (size_t)BB * NN * NN * sizeof(unsigned short);
  const bool use_bf = ws_size >= bf_bytes;
  unsigned short* Abf = use_bf ? (unsigned short*)d_ws : nullptr;

  chi_kernel<<<dim3(BB * NN / 16), dim3(256), 0, stream>>>(feats, W1, b1, W2, b2, W3, b3, chi);
  build_A_kernel<<<dim3(NN / 16, BB), dim3(256), 0, stream>>>(pos, ntype, hardness, sigma, Aout, Abf);
  if (use_bf)
    cg_kernel_bf<<<dim3(BB), dim3(1024), 0, stream>>>(Abf, tq, chi);
  else
    cg_kernel_f32<<<dim3(BB), dim3(1024), 0, stream>>>(Aout, tq, chi);
}